// Round 13
// baseline (354.294 us; speedup 1.0000x reference)
//
#include <hip/hip_runtime.h>
#include <stdint.h>

typedef short short8 __attribute__((ext_vector_type(8)));
typedef float f32x4 __attribute__((ext_vector_type(4)));

#define NPB     100    // n-rows per block; 1000 blocks * 100 = 100000 exactly
#define NPH     50     // row PAIRS per block
#define NBLOCKS 1000

__device__ __forceinline__ uint32_t f32_to_bf16_rne(float f) {
    uint32_t u = __builtin_bit_cast(uint32_t, f);
    uint32_t r = u + 0x7FFFu + ((u >> 16) & 1u);
    return r >> 16;
}
// packed f32x2 -> bf16x2 (RNE), single VALU op
__device__ __forceinline__ uint32_t cvt_pk_bf16(float lo, float hi) {
    uint32_t r;
    asm("v_cvt_pk_bf16_f32 %0, %1, %2" : "=v"(r) : "v"(lo), "v"(hi));
    return r;
}

// async global->LDS, 16B per lane; LDS dest = wave-uniform base + lane*16
#define GLOAD_LDS16(g, l)                                                  \
    __builtin_amdgcn_global_load_lds(                                      \
        (const __attribute__((address_space(1))) void*)(g),                \
        (__attribute__((address_space(3))) void*)(l), 16, 0, 0)

// ---------------------------------------------------------------------------
// Pre-kernel: Wt[l][o][i] = bf16(w_l[i][o])  (transposed so A-fragments are
// contiguous-in-i 16B loads). 4 * 128 * 128 bf16 = 128 KB in d_ws.
// ---------------------------------------------------------------------------
__global__ void conv_weights(const float* __restrict__ w0, const float* __restrict__ w1,
                             const float* __restrict__ w2, const float* __restrict__ w3,
                             uint16_t* __restrict__ wt) {
    int idx = blockIdx.x * 256 + threadIdx.x;   // 0 .. 65535
    int l = idx >> 14;
    int o = (idx >> 7) & 127;
    int i = idx & 127;
    const float* w = (l == 0) ? w0 : (l == 1) ? w1 : (l == 2) ? w2 : w3;
    wt[idx] = (uint16_t)f32_to_bf16_rne(w[i * 128 + o]);
}

// ---------------------------------------------------------------------------
// Main kernel, ROUND 13 = r12 + VECTORIZED STORES.
// r9-r12 post-mortems: bank-conflict fix null, LDS-instr halving null,
// occupancy null -> time pinned at 343-345us = 4.95 TB/s, 79% of m13 copy
// ceiling. The invariant suspect: the WRITE stream was scalar dwords
// (32 instr/row, 4x64B fragments each; 64B straddles 128B L2 sectors),
// while the read stream is dense 1KB extents. This round: 2-stage XOR
// butterfly (shfl_xor 1,2; quad-local; compile-time reg indices, rule #20)
// transposes each c-quad so a lane owns 4 consecutive c for one o ->
// f32x4 stores, one dense 1KB extent per wave-instruction (= load side).
// Stores 32 -> 8 instr/row. vmcnt recounted: 2 loads + 2 stores per
// thread/phase -> steady vmcnt(10), tail vmcnt(6). Never drained.
//
// Transpose algebra: M[a][b] at (lane a, reg b) -> (lane b, reg a) via
// stage1 (xor1, move iff (a^b)&1, reg^=1) + stage2 (xor2, move iff
// (lane^reg)&2, reg^=2); lane^reg invariant. Verified elementwise.
//
// Everything else = r12: 4-slot ring of 16KB row pairs, 3 phases ahead,
// pre-swizzled source granule (LDS idx(i,c)=(i^((i>>3)&1))*16+c; read
// i^(kg&1), free banks), waves 0-3 row 2p / waves 4-7 row 2p+1, 2 o-tiles
// per wave (wfr[2][4][4] register-resident), 4 unmasked l-passes,
// per-lane l(c)-select. MFMA 16x16x32 bf16 (m89-verified layout).
// ---------------------------------------------------------------------------
__global__ void __launch_bounds__(512, 1)
isl_kernel(const float* __restrict__ x,
           const uint16_t* __restrict__ wt,
           float* __restrict__ out) {
    __shared__ uint8_t ldsbuf[4][16384];
    const int tid   = threadIdx.x;
    const int lane  = tid & 63;
    const int wid   = tid >> 6;      // 0..7
    const int rhalf = wid >> 2;      // which row of the pair this wave computes
    const int og    = (wid & 3) * 32; // 32-wide o-group (two 16-tiles)
    const int r16   = lane & 15;     // A-row (o_loc) / B-col & D-col (c)
    const int kg    = lane >> 4;     // 0..3
    const int kx1   = kg & 1;        // read-side swizzle bit
    const int s4    = r16 & 3;       // lane-in-quad (transpose index)
    const int q4    = r16 >> 2;      // c-quad

    // ---- weight fragments: two o-tiles, resident for the whole block
    short8 wfr[2][4][4];             // [tile][l][ks]
    #pragma unroll
    for (int t = 0; t < 2; ++t) {
        const uint16_t* wb = wt + (size_t)(og + t * 16 + r16) * 128 + kg * 8;
        #pragma unroll
        for (int l = 0; l < 4; ++l)
            #pragma unroll
            for (int ks = 0; ks < 4; ++ks)
                wfr[t][l][ks] = *(const short8*)(wb + l * 16384 + ks * 32);
    }

    const int n0 = blockIdx.x * NPB;
    // per-thread global src granule, pre-swizzled (involution, 16B granules)
    const int srcg = tid ^ (((tid >> 5) & 1) << 2);
    const uint8_t* xg = (const uint8_t*)(x + (size_t)n0 * 2048) + (size_t)srcg * 16;

    // ---- prologue: stage phases 0..2 (rows 0..5), drain once, sync
    #pragma unroll
    for (int p = 0; p < 3; ++p)
        #pragma unroll
        for (int h = 0; h < 2; ++h)
            GLOAD_LDS16(xg + (size_t)(2 * p + h) * 8192,
                        &ldsbuf[p][h * 8192 + wid * 1024]);
    asm volatile("s_waitcnt vmcnt(0)" ::: "memory");
    __builtin_amdgcn_s_barrier();

    // per-thread out base: o = og + kg*4 + s4 (+ t*16), c-chunk = q4*4
    float* po_base = out + (size_t)(n0 + rhalf) * 2048 +
                     (size_t)(og + kg * 4 + s4) * 16 + q4 * 4;

    #pragma unroll 1
    for (int p = 0; p < NPH; ++p) {
        if (p > 0) {
            if (p <= NPH - 3)
                asm volatile("s_waitcnt vmcnt(10)" ::: "memory");
            else
                asm volatile("s_waitcnt vmcnt(6)" ::: "memory");
            __builtin_amdgcn_s_barrier();
        }
        // ---- prefetch phase p+3 (slot (p+3)&3 = (p-1)&3, free after barrier)
        if (p + 3 < NPH) {
            GLOAD_LDS16(xg + (size_t)(2 * (p + 3)) * 8192,
                        &ldsbuf[(p + 3) & 3][wid * 1024]);
            GLOAD_LDS16(xg + (size_t)(2 * (p + 3) + 1) * 8192,
                        &ldsbuf[(p + 3) & 3][8192 + wid * 1024]);
        }

        // ---- B fragments from this wave's row half (swizzled read: i ^= kg&1)
        const float* rowp = (const float*)&ldsbuf[p & 3][rhalf * 8192];
        short8 xb[4];
        #pragma unroll
        for (int ks = 0; ks < 4; ++ks) {
            float f[8];
            #pragma unroll
            for (int j = 0; j < 8; ++j)
                f[j] = rowp[((ks * 32 + kg * 8 + j) ^ kx1) * 16 + r16];
            uint32_t q[4];
            #pragma unroll
            for (int h = 0; h < 4; ++h)
                q[h] = cvt_pk_bf16(f[2 * h], f[2 * h + 1]);
            xb[ks] = *(const short8*)q;
        }

        // ---- 2 o-tiles x 4 l-passes, B shared
        f32x4 acc[2][4];
        #pragma unroll
        for (int t = 0; t < 2; ++t)
            #pragma unroll
            for (int l = 0; l < 4; ++l)
                acc[t][l] = (f32x4){0.f, 0.f, 0.f, 0.f};
        #pragma unroll
        for (int t = 0; t < 2; ++t)
            #pragma unroll
            for (int l = 0; l < 4; ++l)
                #pragma unroll
                for (int ks = 0; ks < 4; ++ks)
                    acc[t][l] = __builtin_amdgcn_mfma_f32_16x16x32_bf16(
                        wfr[t][l][ks], xb[ks], acc[t][l], 0, 0, 0);

        // ---- store: l(c)-select, then 4x4 quad transpose -> f32x4 store
        float* po = po_base + (size_t)(2 * p) * 2048;
        #pragma unroll
        for (int t = 0; t < 2; ++t) {
            float vals[4];
            #pragma unroll
            for (int rr = 0; rr < 4; ++rr) {
                float v = acc[t][0][rr];
                v = (r16 >= 1) ? acc[t][1][rr] : v;
                v = (r16 >= 4) ? acc[t][2][rr] : v;
                v = (r16 >= 9) ? acc[t][3][rr] : v;
                vals[rr] = v;
            }
            float u[4], w[4];
            #pragma unroll
            for (int i = 0; i < 4; ++i) {
                float ex = __shfl_xor(vals[i ^ 1], 1, 64);
                u[i] = ((s4 ^ i) & 1) ? ex : vals[i];
            }
            #pragma unroll
            for (int i = 0; i < 4; ++i) {
                float ex = __shfl_xor(u[i ^ 2], 2, 64);
                w[i] = ((s4 ^ i) & 2) ? ex : u[i];
            }
            f32x4 o4 = {w[0], w[1], w[2], w[3]};
            *(f32x4*)(po + t * 256) = o4;   // 16B aligned; wave = dense 1KB extent
        }
    }
}

extern "C" void kernel_launch(void* const* d_in, const int* in_sizes, int n_in,
                              void* d_out, int out_size, void* d_ws, size_t ws_size,
                              hipStream_t stream) {
    const float* x  = (const float*)d_in[0];
    const float* w0 = (const float*)d_in[1];
    const float* w1 = (const float*)d_in[2];
    const float* w2 = (const float*)d_in[3];
    const float* w3 = (const float*)d_in[4];
    uint16_t* wt = (uint16_t*)d_ws;          // 128 KB scratch
    float* out = (float*)d_out;

    conv_weights<<<256, 256, 0, stream>>>(w0, w1, w2, w3, wt);
    isl_kernel<<<NBLOCKS, 512, 0, stream>>>(x, wt, out);
}

// Round 14
// 346.585 us; speedup vs baseline: 1.0222x; 1.0222x over previous
//
#include <hip/hip_runtime.h>
#include <stdint.h>

typedef short short8 __attribute__((ext_vector_type(8)));
typedef float f32x4 __attribute__((ext_vector_type(4)));

#define NPB     100    // n-rows per block; 1000 blocks * 100 = 100000 exactly
#define NPH     50     // row PAIRS per block
#define NBLOCKS 1000

__device__ __forceinline__ uint32_t f32_to_bf16_rne(float f) {
    uint32_t u = __builtin_bit_cast(uint32_t, f);
    uint32_t r = u + 0x7FFFu + ((u >> 16) & 1u);
    return r >> 16;
}
// packed f32x2 -> bf16x2 (RNE), single VALU op
__device__ __forceinline__ uint32_t cvt_pk_bf16(float lo, float hi) {
    uint32_t r;
    asm("v_cvt_pk_bf16_f32 %0, %1, %2" : "=v"(r) : "v"(lo), "v"(hi));
    return r;
}

// async global->LDS, 16B per lane; LDS dest = wave-uniform base + lane*16
#define GLOAD_LDS16(g, l)                                                  \
    __builtin_amdgcn_global_load_lds(                                      \
        (const __attribute__((address_space(1))) void*)(g),                \
        (__attribute__((address_space(3))) void*)(l), 16, 0, 0)

// ---------------------------------------------------------------------------
// Pre-kernel: Wt[l][o][i] = bf16(w_l[i][o])  (transposed so A-fragments are
// contiguous-in-i 16B loads). 4 * 128 * 128 bf16 = 128 KB in d_ws.
// ---------------------------------------------------------------------------
__global__ void conv_weights(const float* __restrict__ w0, const float* __restrict__ w1,
                             const float* __restrict__ w2, const float* __restrict__ w3,
                             uint16_t* __restrict__ wt) {
    int idx = blockIdx.x * 256 + threadIdx.x;   // 0 .. 65535
    int l = idx >> 14;
    int o = (idx >> 7) & 127;
    int i = idx & 127;
    const float* w = (l == 0) ? w0 : (l == 1) ? w1 : (l == 2) ? w2 : w3;
    wt[idx] = (uint16_t)f32_to_bf16_rne(w[i * 128 + o]);
}

// ---------------------------------------------------------------------------
// Main kernel, ROUND 14 = r12 (343us best) + DEEPER RING: 4->6 slots,
// prefetch distance 3->5. (r13's store transpose REVERTED: -3%.)
//
// Rationale: 4 compute-side nulls (bank conflicts, LDS instr rate, store
// width, occupancy) pin time at 343us = 76% of m13 copy ceiling. Remaining
// arithmetic suspect: in-flight read depth vs LOADED latency. At 3-ahead,
// avg outstanding reads ~30 KB/CU; required = 10.25 B/cy x loaded-latency
// (~2500-3000cy under full-fabric contention) = 26-31 KB -> borderline,
// and the phase-locked 16 KB bursts make the average sag. 5-ahead doubles
// it (peak 80 KB/CU, avg ~55-60) -> load-return equilibrium moves from
// latency-limited to BW-limited.
//
// vmcnt (per thread per phase: 2 gload_lds + 8 stores, distance 5):
//   ops younger than L(p) at wait(p), steady = S(p-5..p-1) 5x8 + L(p+1..p+4)
//   4x2 = 48 -> vmcnt(48) for 5 <= p <= NPH-5; tail p > NPH-5: true count
//   40+2(NPH-1-p), use conservative vmcnt(40); warmup p in [1,4]: no wait
//   (compute(p) reads prologue-drained slots; barrier alone guards slot
//   reuse). NEVER drained in steady state.
// Slots: compute p%6, prefetch (p+5)%6 (= (p-1)%6, freed by barrier(p));
// rotating counters avoid runtime mod.
//
// Everything else = r12: pre-swizzled source granule (LDS idx(i,c) =
// (i^((i>>3)&1))*16+c; read i^(kg&1) -> conflict-free), waves 0-3 row 2p /
// waves 4-7 row 2p+1, 2 o-tiles per wave (wfr[2][4][4] register-resident),
// 4 unmasked l-passes into acc[t][l], per-lane l(c)-select, scalar stores.
// MFMA 16x16x32 bf16 (m89-verified layout).
// ---------------------------------------------------------------------------
__global__ void __launch_bounds__(512, 1)
isl_kernel(const float* __restrict__ x,
           const uint16_t* __restrict__ wt,
           float* __restrict__ out) {
    __shared__ uint8_t ldsbuf[6][16384];   // 96 KB ring
    const int tid   = threadIdx.x;
    const int lane  = tid & 63;
    const int wid   = tid >> 6;      // 0..7
    const int rhalf = wid >> 2;      // which row of the pair this wave computes
    const int og    = (wid & 3) * 32; // 32-wide o-group (two 16-tiles)
    const int r16   = lane & 15;     // A-row (o_loc) / B-col & D-col (c)
    const int kg    = lane >> 4;     // 0..3
    const int kx1   = kg & 1;        // read-side swizzle bit

    // ---- weight fragments: two o-tiles, resident for the whole block
    short8 wfr[2][4][4];             // [tile][l][ks]
    #pragma unroll
    for (int t = 0; t < 2; ++t) {
        const uint16_t* wb = wt + (size_t)(og + t * 16 + r16) * 128 + kg * 8;
        #pragma unroll
        for (int l = 0; l < 4; ++l)
            #pragma unroll
            for (int ks = 0; ks < 4; ++ks)
                wfr[t][l][ks] = *(const short8*)(wb + l * 16384 + ks * 32);
    }

    const int n0 = blockIdx.x * NPB;
    // per-thread global src granule, pre-swizzled (involution, 16B granules)
    const int srcg = tid ^ (((tid >> 5) & 1) << 2);
    const uint8_t* xg = (const uint8_t*)(x + (size_t)n0 * 2048) + (size_t)srcg * 16;

    // ---- prologue: stage phases 0..4 (rows 0..9), drain once, sync
    #pragma unroll
    for (int p = 0; p < 5; ++p)
        #pragma unroll
        for (int h = 0; h < 2; ++h)
            GLOAD_LDS16(xg + (size_t)(2 * p + h) * 8192,
                        &ldsbuf[p][h * 8192 + wid * 1024]);
    asm volatile("s_waitcnt vmcnt(0)" ::: "memory");
    __builtin_amdgcn_s_barrier();

    // per-thread out base for this wave's row-half and o-group
    float* po_base = out + (size_t)(n0 + rhalf) * 2048 +
                     (size_t)(og + kg * 4) * 16 + r16;

    int cs = 0;   // compute slot  = p % 6
    int ps = 5;   // prefetch slot = (p+5) % 6

    #pragma unroll 1
    for (int p = 0; p < NPH; ++p) {
        if (p > 0) {
            if (p >= 5) {
                if (p <= NPH - 5)
                    asm volatile("s_waitcnt vmcnt(48)" ::: "memory");
                else
                    asm volatile("s_waitcnt vmcnt(40)" ::: "memory");
            }
            __builtin_amdgcn_s_barrier();
        }
        // ---- prefetch phase p+5 into slot (p+5)%6 (freed by this barrier)
        if (p + 5 < NPH) {
            GLOAD_LDS16(xg + (size_t)(2 * (p + 5)) * 8192,
                        &ldsbuf[ps][wid * 1024]);
            GLOAD_LDS16(xg + (size_t)(2 * (p + 5) + 1) * 8192,
                        &ldsbuf[ps][8192 + wid * 1024]);
        }

        // ---- B fragments from this wave's row half (swizzled read: i ^= kg&1)
        const float* rowp = (const float*)&ldsbuf[cs][rhalf * 8192];
        short8 xb[4];
        #pragma unroll
        for (int ks = 0; ks < 4; ++ks) {
            float f[8];
            #pragma unroll
            for (int j = 0; j < 8; ++j)
                f[j] = rowp[((ks * 32 + kg * 8 + j) ^ kx1) * 16 + r16];
            uint32_t q[4];
            #pragma unroll
            for (int h = 0; h < 4; ++h)
                q[h] = cvt_pk_bf16(f[2 * h], f[2 * h + 1]);
            xb[ks] = *(const short8*)q;
        }

        // ---- 2 o-tiles x 4 l-passes, B shared
        f32x4 acc[2][4];
        #pragma unroll
        for (int t = 0; t < 2; ++t)
            #pragma unroll
            for (int l = 0; l < 4; ++l)
                acc[t][l] = (f32x4){0.f, 0.f, 0.f, 0.f};
        #pragma unroll
        for (int t = 0; t < 2; ++t)
            #pragma unroll
            for (int l = 0; l < 4; ++l)
                #pragma unroll
                for (int ks = 0; ks < 4; ++ks)
                    acc[t][l] = __builtin_amdgcn_mfma_f32_16x16x32_bf16(
                        wfr[t][l][ks], xb[ks], acc[t][l], 0, 0, 0);

        // ---- store: row = 2p + rhalf; per tile 4 dwords, per-lane l(c)-select
        float* po = po_base + (size_t)(2 * p) * 2048;
        #pragma unroll
        for (int t = 0; t < 2; ++t) {
            #pragma unroll
            for (int rr = 0; rr < 4; ++rr) {
                float v = acc[t][0][rr];
                v = (r16 >= 1) ? acc[t][1][rr] : v;
                v = (r16 >= 4) ? acc[t][2][rr] : v;
                v = (r16 >= 9) ? acc[t][3][rr] : v;
                po[(t * 16 + rr) * 16] = v;
            }
        }

        cs = (cs == 5) ? 0 : cs + 1;
        ps = (ps == 5) ? 0 : ps + 1;
    }
}

extern "C" void kernel_launch(void* const* d_in, const int* in_sizes, int n_in,
                              void* d_out, int out_size, void* d_ws, size_t ws_size,
                              hipStream_t stream) {
    const float* x  = (const float*)d_in[0];
    const float* w0 = (const float*)d_in[1];
    const float* w1 = (const float*)d_in[2];
    const float* w2 = (const float*)d_in[3];
    const float* w3 = (const float*)d_in[4];
    uint16_t* wt = (uint16_t*)d_ws;          // 128 KB scratch
    float* out = (float*)d_out;

    conv_weights<<<256, 256, 0, stream>>>(w0, w1, w2, w3, wt);
    isl_kernel<<<NBLOCKS, 512, 0, stream>>>(x, wt, out);
}